// Round 2
// baseline (469.458 us; speedup 1.0000x reference)
//
#include <hip/hip_runtime.h>
#include <math.h>

#define DIM 512
#define CHUNK 32

// -------- Kernel 1: exclusive scan of lengths -> segment start offsets ------
__global__ void scan_lengths_kernel(const int* __restrict__ lengths,
                                    int* __restrict__ starts, int B) {
    __shared__ int buf[1024];
    const int tid = threadIdx.x;
    int carry = 0;
    for (int base = 0; base < B; base += 1024) {
        const int i = base + tid;
        const int v = (i < B) ? lengths[i] : 0;
        buf[tid] = v;
        __syncthreads();
        // Hillis-Steele inclusive scan over 1024 entries
        for (int off = 1; off < 1024; off <<= 1) {
            const int add = (tid >= off) ? buf[tid - off] : 0;
            __syncthreads();
            buf[tid] += add;
            __syncthreads();
        }
        if (i < B) starts[i] = carry + buf[tid] - v;   // exclusive
        carry += buf[1023];
        __syncthreads();
    }
}

// -------- Kernel 2: per-segment online prefix-softmax weighted average ------
// One 256-thread block per segment. Per 32-token chunk:
//   Phase A: 4 waves compute scores (dot with theta) via coalesced row loads
//            + wave shuffle-reduce; scores -> LDS.
//   Rescale: online-max update (num/den ratio is stabilizer-invariant, so a
//            running prefix max is mathematically identical to the reference's
//            full-segment max).
//   Phase B: token-sequential scan; thread owns columns (2*tid, 2*tid+1);
//            coalesced float2 load/store per token.
__global__ __launch_bounds__(256) void seg_prefix_softmax_kernel(
    const float* __restrict__ ctx, const float* __restrict__ theta,
    const int* __restrict__ lengths, const int* __restrict__ starts,
    float* __restrict__ out) {
    const int b    = blockIdx.x;
    const int tid  = threadIdx.x;
    const int lane = tid & 63;
    const int wave = tid >> 6;
    const int start = starts[b];
    const int len   = lengths[b];

    __shared__ __align__(16) float s_theta[DIM];
    __shared__ float s_sc[CHUNK];

    s_theta[tid]       = theta[tid];
    s_theta[tid + 256] = theta[tid + 256];
    __syncthreads();

    // Per-lane theta slice for the dot product (lane covers 8 consecutive d)
    const float4 th0 = *(const float4*)&s_theta[lane * 8];
    const float4 th1 = *(const float4*)&s_theta[lane * 8 + 4];

    const float* __restrict__ base  = ctx + (long long)start * DIM;
    float*       __restrict__ obase = out + (long long)start * DIM;

    float2 num  = make_float2(0.f, 0.f);
    float  den  = 0.f;
    float  runm = -INFINITY;

    for (int cb = 0; cb < len; cb += CHUNK) {
        const int cn = min(CHUNK, len - cb);

        // ---- Phase A: chunk scores ----
        for (int tl = wave; tl < cn; tl += 4) {
            const float* row = base + (long long)(cb + tl) * DIM + lane * 8;
            const float4 a  = *(const float4*)row;
            const float4 a2 = *(const float4*)(row + 4);
            float p = a.x * th0.x + a.y * th0.y + a.z * th0.z + a.w * th0.w
                    + a2.x * th1.x + a2.y * th1.y + a2.z * th1.z + a2.w * th1.w;
            #pragma unroll
            for (int off = 32; off >= 1; off >>= 1) p += __shfl_xor(p, off, 64);
            if (lane == 0) s_sc[tl] = p;
        }
        __syncthreads();

        // ---- online-max rescale (redundant per-thread, LDS broadcast) ----
        float cm = -INFINITY;
        for (int i = 0; i < cn; ++i) cm = fmaxf(cm, s_sc[i]);
        const float new_m = fmaxf(runm, cm);
        const float scale = __expf(runm - new_m);  // first chunk: exp(-inf)=0
        num.x *= scale; num.y *= scale; den *= scale;
        runm = new_m;

        // ---- Phase B: sequential prefix scan over chunk tokens ----
        const float* cptr = base  + (long long)cb * DIM + tid * 2;
        float*       optr = obase + (long long)cb * DIM + tid * 2;
        for (int i = 0; i < cn; ++i) {
            const float2 c = *(const float2*)(cptr + (long long)i * DIM);
            const float  e = __expf(s_sc[i] - runm);
            den += e;
            num.x = fmaf(e, c.x, num.x);
            num.y = fmaf(e, c.y, num.y);
            const float r = __builtin_amdgcn_rcpf(den);
            const float2 o = make_float2(num.x * r, num.y * r);
            *(float2*)(optr + (long long)i * DIM) = o;
        }
        __syncthreads();  // s_sc reused next chunk
    }
}

extern "C" void kernel_launch(void* const* d_in, const int* in_sizes, int n_in,
                              void* d_out, int out_size, void* d_ws, size_t ws_size,
                              hipStream_t stream) {
    const float* ctx     = (const float*)d_in[0];   // [T, 512] fp32
    const float* theta   = (const float*)d_in[1];   // [512, 1] fp32
    const int*   lengths = (const int*)d_in[2];     // [B] int32
    // d_in[3] (seg_ids) is redundant given lengths.
    float* out = (float*)d_out;                     // [T, 512] fp32

    const int B = in_sizes[2];
    int* starts = (int*)d_ws;                       // B ints of scratch

    scan_lengths_kernel<<<1, 1024, 0, stream>>>(lengths, starts, B);
    seg_prefix_softmax_kernel<<<B, 256, 0, stream>>>(ctx, theta, lengths, starts, out);
}